// Round 1
// baseline (2226.833 us; speedup 1.0000x reference)
//
#include <hip/hip_runtime.h>
#include <math.h>

#define NN 100000
#define NE 1600000
#define HID 128
#define INCH 256
#define OUTC 40
#define NLAYERS 8

// ---------------- preprocessing kernels ----------------

static __global__ void k_zero(int* __restrict__ cnt) {
  int i = blockIdx.x * 256 + threadIdx.x;
  if (i < NN) cnt[i] = 0;
}

static __global__ void k_hist(const int* __restrict__ ei, int* __restrict__ cnt) {
  int e = blockIdx.x * 256 + threadIdx.x;
  if (e < NE) atomicAdd(&cnt[ei[NE + e]], 1);
}

static __global__ void k_dinv(const int* __restrict__ cnt, float* __restrict__ dinv,
                              int* __restrict__ offs) {
  int i = blockIdx.x * 256 + threadIdx.x;
  if (i < NN) dinv[i] = rsqrtf((float)(cnt[i] + 1));  // +1 self loop; always > 0
  if (blockIdx.x == 0 && threadIdx.x == 0) offs[NN] = NE;
}

static __global__ void k_scan1(const int* __restrict__ cnt, int* __restrict__ bsum) {
  __shared__ int sd[256];
  int t = threadIdx.x;
  int gid = blockIdx.x * 256 + t;
  sd[t] = (gid < NN) ? cnt[gid] : 0;
  __syncthreads();
  for (int s = 128; s > 0; s >>= 1) {
    if (t < s) sd[t] += sd[t + s];
    __syncthreads();
  }
  if (t == 0) bsum[blockIdx.x] = sd[0];
}

static __global__ void k_scan2(int* __restrict__ bsum, int nb) {
  __shared__ int sd[512];
  int t = threadIdx.x;
  sd[t] = (t < nb) ? bsum[t] : 0;
  __syncthreads();
  for (int d = 1; d < 512; d <<= 1) {
    int v = (t >= d) ? sd[t - d] : 0;
    __syncthreads();
    sd[t] += v;
    __syncthreads();
  }
  if (t < nb) bsum[t] = sd[t];  // inclusive scan
}

static __global__ void k_scan3(const int* __restrict__ cnt, const int* __restrict__ bsum,
                               int* __restrict__ offs, int* __restrict__ cursor) {
  __shared__ int sd[256];
  int t = threadIdx.x;
  int gid = blockIdx.x * 256 + t;
  int v = (gid < NN) ? cnt[gid] : 0;
  sd[t] = v;
  __syncthreads();
  for (int d = 1; d < 256; d <<= 1) {
    int u = (t >= d) ? sd[t - d] : 0;
    __syncthreads();
    sd[t] += u;
    __syncthreads();
  }
  int base = (blockIdx.x > 0) ? bsum[blockIdx.x - 1] : 0;
  int excl = base + sd[t] - v;
  if (gid < NN) { offs[gid] = excl; cursor[gid] = excl; }
}

static __global__ void k_fill(const int* __restrict__ ei, const float* __restrict__ dinv,
                              int* __restrict__ cursor, int* __restrict__ esrc,
                              float* __restrict__ ew) {
  int e = blockIdx.x * 256 + threadIdx.x;
  if (e < NE) {
    int s = ei[e];        // row = source
    int d = ei[NE + e];   // col = target (aggregation)
    int pos = atomicAdd(&cursor[d], 1);
    esrc[pos] = s;
    ew[pos] = dinv[s] * dinv[d];
  }
}

// ---------------- GEMM: C[M x 128] = epi(A[M x K] @ W[K x 128]) ----------------
// 256 threads, tile 128 rows x 128 cols, 8x8 microtile.
// EPI 0: relu(z + bias[c]);  EPI 1: relu((1-beta)*A[r][c] + beta*z)  (A==hc, K==128)
template <int K, int EPI>
__global__ __launch_bounds__(256) void k_gemm(const float* __restrict__ A,
                                              const float* __restrict__ W,
                                              const float* __restrict__ bias, float beta,
                                              float* __restrict__ C, int M) {
  __shared__ float At[32][132];  // transposed A tile; 132*4=528B rows, 16B aligned
  __shared__ float Wt[32][128];

  const int tid = threadIdx.x;
  const int tc = tid & 15;   // col group: cols {tc*4..+3} U {64+tc*4..+3}
  const int tr = tid >> 4;   // row group: rows tr*8..tr*8+7
  const int m0 = blockIdx.x * 128;

  float acc[8][8];
#pragma unroll
  for (int i = 0; i < 8; ++i)
#pragma unroll
    for (int j = 0; j < 8; ++j) acc[i][j] = 0.f;

  const int ar = tid >> 1;          // 0..127: tile row to stage
  const int ak = (tid & 1) * 16;    // 0 or 16: k sub-chunk
  const int wr = tid >> 3;          // 0..31: W row to stage
  const int wq = (tid & 7) * 16;    // col start

  for (int kc = 0; kc < K; kc += 32) {
    __syncthreads();
    {  // stage A (transposed)
      int grow = m0 + ar;
      float4 v0 = {0, 0, 0, 0}, v1 = {0, 0, 0, 0}, v2 = {0, 0, 0, 0}, v3 = {0, 0, 0, 0};
      if (grow < M) {
        const float* p = A + (size_t)grow * K + kc + ak;
        v0 = *(const float4*)p;
        v1 = *(const float4*)(p + 4);
        v2 = *(const float4*)(p + 8);
        v3 = *(const float4*)(p + 12);
      }
      At[ak + 0][ar] = v0.x;  At[ak + 1][ar] = v0.y;  At[ak + 2][ar] = v0.z;  At[ak + 3][ar] = v0.w;
      At[ak + 4][ar] = v1.x;  At[ak + 5][ar] = v1.y;  At[ak + 6][ar] = v1.z;  At[ak + 7][ar] = v1.w;
      At[ak + 8][ar] = v2.x;  At[ak + 9][ar] = v2.y;  At[ak + 10][ar] = v2.z; At[ak + 11][ar] = v2.w;
      At[ak + 12][ar] = v3.x; At[ak + 13][ar] = v3.y; At[ak + 14][ar] = v3.z; At[ak + 15][ar] = v3.w;
    }
    {  // stage W (row-major)
      const float* p = W + (size_t)(kc + wr) * HID + wq;
      float4 u0 = *(const float4*)p, u1 = *(const float4*)(p + 4);
      float4 u2 = *(const float4*)(p + 8), u3 = *(const float4*)(p + 12);
      *(float4*)&Wt[wr][wq + 0] = u0;
      *(float4*)&Wt[wr][wq + 4] = u1;
      *(float4*)&Wt[wr][wq + 8] = u2;
      *(float4*)&Wt[wr][wq + 12] = u3;
    }
    __syncthreads();
#pragma unroll 4
    for (int k = 0; k < 32; ++k) {
      float a[8], b[8];
      *(float4*)&a[0] = *(const float4*)&At[k][tr * 8];
      *(float4*)&a[4] = *(const float4*)&At[k][tr * 8 + 4];
      *(float4*)&b[0] = *(const float4*)&Wt[k][tc * 4];
      *(float4*)&b[4] = *(const float4*)&Wt[k][64 + tc * 4];
#pragma unroll
      for (int i = 0; i < 8; ++i)
#pragma unroll
        for (int j = 0; j < 8; ++j) acc[i][j] = fmaf(a[i], b[j], acc[i][j]);
    }
  }

  const int c0 = tc * 4, c1 = 64 + tc * 4;
#pragma unroll
  for (int i = 0; i < 8; ++i) {
    int r = m0 + tr * 8 + i;
    if (r >= M) continue;
    float4 z0 = {acc[i][0], acc[i][1], acc[i][2], acc[i][3]};
    float4 z1 = {acc[i][4], acc[i][5], acc[i][6], acc[i][7]};
    if constexpr (EPI == 0) {
      float4 bb0 = *(const float4*)&bias[c0];
      float4 bb1 = *(const float4*)&bias[c1];
      z0.x = fmaxf(z0.x + bb0.x, 0.f); z0.y = fmaxf(z0.y + bb0.y, 0.f);
      z0.z = fmaxf(z0.z + bb0.z, 0.f); z0.w = fmaxf(z0.w + bb0.w, 0.f);
      z1.x = fmaxf(z1.x + bb1.x, 0.f); z1.y = fmaxf(z1.y + bb1.y, 0.f);
      z1.z = fmaxf(z1.z + bb1.z, 0.f); z1.w = fmaxf(z1.w + bb1.w, 0.f);
    } else {
      const float ob = 1.f - beta;
      float4 h0 = *(const float4*)&A[(size_t)r * K + c0];
      float4 h1 = *(const float4*)&A[(size_t)r * K + c1];
      z0.x = fmaxf(ob * h0.x + beta * z0.x, 0.f); z0.y = fmaxf(ob * h0.y + beta * z0.y, 0.f);
      z0.z = fmaxf(ob * h0.z + beta * z0.z, 0.f); z0.w = fmaxf(ob * h0.w + beta * z0.w, 0.f);
      z1.x = fmaxf(ob * h1.x + beta * z1.x, 0.f); z1.y = fmaxf(ob * h1.y + beta * z1.y, 0.f);
      z1.z = fmaxf(ob * h1.z + beta * z1.z, 0.f); z1.w = fmaxf(ob * h1.w + beta * z1.w, 0.f);
    }
    *(float4*)&C[(size_t)r * HID + c0] = z0;
    *(float4*)&C[(size_t)r * HID + c1] = z1;
  }
}

// ---------------- aggregation: hc = 0.5*(A_hat @ h) + 0.5*x0 ----------------
static __global__ __launch_bounds__(128) void k_agg(
    const float* __restrict__ h, const float* __restrict__ x0,
    const float* __restrict__ dinv, const int* __restrict__ offs,
    const int* __restrict__ esrc, const float* __restrict__ ew,
    float* __restrict__ hc) {
  int n = blockIdx.x;
  int c = threadIdx.x;
  int b = offs[n], e = offs[n + 1];
  float dn = dinv[n];
  size_t nc = (size_t)n * HID + c;
  float acc = h[nc] * (dn * dn);  // self loop
  for (int i = b; i < e; ++i) {
    int s = esrc[i];
    float w = ew[i];
    acc = fmaf(h[(size_t)s * HID + c], w, acc);
  }
  hc[nc] = 0.5f * acc + 0.5f * x0[nc];
}

// ---------------- lin2 + log_softmax (wave per row) ----------------
static __global__ __launch_bounds__(256) void k_lin2(const float* __restrict__ h,
                                                     const float* __restrict__ W2,
                                                     const float* __restrict__ b2,
                                                     float* __restrict__ out) {
  __shared__ float sW[HID * OUTC];  // 20 KB
  __shared__ float sh[4][HID];
  for (int i = threadIdx.x; i < HID * OUTC; i += 256) sW[i] = W2[i];
  int wid = threadIdx.x >> 6, lane = threadIdx.x & 63;
  int r = blockIdx.x * 4 + wid;
  bool valid = r < NN;
  if (valid) {
    sh[wid][lane] = h[(size_t)r * HID + lane];
    sh[wid][64 + lane] = h[(size_t)r * HID + 64 + lane];
  }
  __syncthreads();
  if (!valid) return;
  float acc = (lane < OUTC) ? b2[lane] : -1e30f;
  if (lane < OUTC) {
#pragma unroll 8
    for (int k = 0; k < HID; ++k) acc = fmaf(sh[wid][k], sW[k * OUTC + lane], acc);
  }
  float m = acc;
  for (int d = 32; d; d >>= 1) m = fmaxf(m, __shfl_xor(m, d));
  float ex = (lane < OUTC) ? __expf(acc - m) : 0.f;
  float ssum = ex;
  for (int d = 32; d; d >>= 1) ssum += __shfl_xor(ssum, d);
  if (lane < OUTC) out[(size_t)r * OUTC + lane] = acc - m - logf(ssum);
}

// ---------------- host ----------------
extern "C" void kernel_launch(void* const* d_in, const int* in_sizes, int n_in,
                              void* d_out, int out_size, void* d_ws, size_t ws_size,
                              hipStream_t stream) {
  const float* x  = (const float*)d_in[0];
  const int*   ei = (const int*)d_in[1];
  const float* w1 = (const float*)d_in[2];
  const float* b1 = (const float*)d_in[3];
  const float* cw = (const float*)d_in[4];
  const float* w2 = (const float*)d_in[5];
  const float* b2 = (const float*)d_in[6];
  float* out = (float*)d_out;

  char* ws = (char*)d_ws;
  size_t o = 0;
  auto carve = [&](size_t bytes) {
    void* p = ws + o;
    o = (o + bytes + 255) & ~(size_t)255;
    return p;
  };
  int*   cnt    = (int*)carve((size_t)NN * 4);
  float* dinv   = (float*)carve((size_t)NN * 4);
  int*   offs   = (int*)carve((size_t)(NN + 1) * 4);
  int*   cursor = (int*)carve((size_t)NN * 4);
  int*   bsum   = (int*)carve(512 * 4);
  int*   esrc   = (int*)carve((size_t)NE * 4);
  float* ewt    = (float*)carve((size_t)NE * 4);
  float* x0     = (float*)carve((size_t)NN * HID * 4);
  float* hb     = (float*)carve((size_t)NN * HID * 4);
  float* hcb    = (float*)carve((size_t)NN * HID * 4);
  (void)ws_size; (void)in_sizes; (void)n_in; (void)out_size;

  const int TB = 256;
  const int gN = (NN + TB - 1) / TB;  // 391
  const int gE = (NE + TB - 1) / TB;  // 6250

  k_zero<<<gN, TB, 0, stream>>>(cnt);
  k_hist<<<gE, TB, 0, stream>>>(ei, cnt);
  k_dinv<<<gN, TB, 0, stream>>>(cnt, dinv, offs);
  k_scan1<<<gN, TB, 0, stream>>>(cnt, bsum);
  k_scan2<<<1, 512, 0, stream>>>(bsum, gN);
  k_scan3<<<gN, TB, 0, stream>>>(cnt, bsum, offs, cursor);
  k_fill<<<gE, TB, 0, stream>>>(ei, dinv, cursor, esrc, ewt);

  const int gG = (NN + 127) / 128;  // 782
  k_gemm<INCH, 0><<<gG, 256, 0, stream>>>(x, w1, b1, 0.f, x0, NN);

  const float* hin = x0;
  for (int l = 0; l < NLAYERS; ++l) {
    float beta = logf(1.0f / (float)(l + 1) + 1.0f);
    k_agg<<<NN, 128, 0, stream>>>(hin, x0, dinv, offs, esrc, ewt, hcb);
    k_gemm<HID, 1><<<gG, 256, 0, stream>>>(hcb, cw + (size_t)l * HID * HID, nullptr, beta, hb, NN);
    hin = hb;
  }
  k_lin2<<<(NN + 3) / 4, 256, 0, stream>>>(hb, w2, b2, out);
}

// Round 2
// 1423.071 us; speedup vs baseline: 1.5648x; 1.5648x over previous
//
#include <hip/hip_runtime.h>
#include <math.h>

#define NN 100000
#define NE 1600000
#define HID 128
#define INCH 256
#define OUTC 40
#define NLAYERS 8

static __device__ inline unsigned short f2bf(float f) {
  unsigned u = __float_as_uint(f);
  unsigned r = (u + 0x7fff + ((u >> 16) & 1)) >> 16;
  return (unsigned short)r;
}

// ---------------- preprocessing kernels ----------------

static __global__ void k_zero(int* __restrict__ cnt) {
  int i = blockIdx.x * 256 + threadIdx.x;
  if (i < NN) cnt[i] = 0;
}

static __global__ void k_hist(const int* __restrict__ ei, int* __restrict__ cnt) {
  int e = blockIdx.x * 256 + threadIdx.x;
  if (e < NE) atomicAdd(&cnt[ei[NE + e]], 1);
}

static __global__ void k_dinv(const int* __restrict__ cnt, float* __restrict__ dinv,
                              int* __restrict__ offs) {
  int i = blockIdx.x * 256 + threadIdx.x;
  if (i < NN) dinv[i] = rsqrtf((float)(cnt[i] + 1));  // +1 self loop; always > 0
  if (blockIdx.x == 0 && threadIdx.x == 0) offs[NN] = NE;
}

static __global__ void k_scan1(const int* __restrict__ cnt, int* __restrict__ bsum) {
  __shared__ int sd[256];
  int t = threadIdx.x;
  int gid = blockIdx.x * 256 + t;
  sd[t] = (gid < NN) ? cnt[gid] : 0;
  __syncthreads();
  for (int s = 128; s > 0; s >>= 1) {
    if (t < s) sd[t] += sd[t + s];
    __syncthreads();
  }
  if (t == 0) bsum[blockIdx.x] = sd[0];
}

static __global__ void k_scan2(int* __restrict__ bsum, int nb) {
  __shared__ int sd[512];
  int t = threadIdx.x;
  sd[t] = (t < nb) ? bsum[t] : 0;
  __syncthreads();
  for (int d = 1; d < 512; d <<= 1) {
    int v = (t >= d) ? sd[t - d] : 0;
    __syncthreads();
    sd[t] += v;
    __syncthreads();
  }
  if (t < nb) bsum[t] = sd[t];  // inclusive scan
}

static __global__ void k_scan3(const int* __restrict__ cnt, const int* __restrict__ bsum,
                               int* __restrict__ offs, int* __restrict__ cursor) {
  __shared__ int sd[256];
  int t = threadIdx.x;
  int gid = blockIdx.x * 256 + t;
  int v = (gid < NN) ? cnt[gid] : 0;
  sd[t] = v;
  __syncthreads();
  for (int d = 1; d < 256; d <<= 1) {
    int u = (t >= d) ? sd[t - d] : 0;
    __syncthreads();
    sd[t] += u;
    __syncthreads();
  }
  int base = (blockIdx.x > 0) ? bsum[blockIdx.x - 1] : 0;
  int excl = base + sd[t] - v;
  if (gid < NN) { offs[gid] = excl; cursor[gid] = excl; }
}

static __global__ void k_fill(const int* __restrict__ ei, const float* __restrict__ dinv,
                              int* __restrict__ cursor, int2* __restrict__ edata) {
  int e = blockIdx.x * 256 + threadIdx.x;
  if (e < NE) {
    int s = ei[e];        // row = source
    int d = ei[NE + e];   // col = target (aggregation)
    int pos = atomicAdd(&cursor[d], 1);
    edata[pos] = make_int2(s, __float_as_int(dinv[s] * dinv[d]));
  }
}

// ---------------- GEMM: C[M x 128] = epi(A[M x K] @ W[K x 128]) ----------------
// 256 threads, tile 128 rows x 128 cols, 8x8 microtile.
// EPI 0: relu(z + bias[c]) -> writes C32 (f32) AND C16 (bf16)
// EPI 1: relu((1-beta)*A[r][c] + beta*z) -> writes C16 (bf16) only
template <int K, int EPI>
__global__ __launch_bounds__(256) void k_gemm(const float* __restrict__ A,
                                              const float* __restrict__ W,
                                              const float* __restrict__ bias, float beta,
                                              float* __restrict__ C32,
                                              unsigned short* __restrict__ C16, int M) {
  __shared__ float At[32][132];
  __shared__ float Wt[32][128];

  const int tid = threadIdx.x;
  const int tc = tid & 15;
  const int tr = tid >> 4;
  const int m0 = blockIdx.x * 128;

  float acc[8][8];
#pragma unroll
  for (int i = 0; i < 8; ++i)
#pragma unroll
    for (int j = 0; j < 8; ++j) acc[i][j] = 0.f;

  const int ar = tid >> 1;
  const int ak = (tid & 1) * 16;
  const int wr = tid >> 3;
  const int wq = (tid & 7) * 16;

  for (int kc = 0; kc < K; kc += 32) {
    __syncthreads();
    {
      int grow = m0 + ar;
      float4 v0 = {0, 0, 0, 0}, v1 = {0, 0, 0, 0}, v2 = {0, 0, 0, 0}, v3 = {0, 0, 0, 0};
      if (grow < M) {
        const float* p = A + (size_t)grow * K + kc + ak;
        v0 = *(const float4*)p;
        v1 = *(const float4*)(p + 4);
        v2 = *(const float4*)(p + 8);
        v3 = *(const float4*)(p + 12);
      }
      At[ak + 0][ar] = v0.x;  At[ak + 1][ar] = v0.y;  At[ak + 2][ar] = v0.z;  At[ak + 3][ar] = v0.w;
      At[ak + 4][ar] = v1.x;  At[ak + 5][ar] = v1.y;  At[ak + 6][ar] = v1.z;  At[ak + 7][ar] = v1.w;
      At[ak + 8][ar] = v2.x;  At[ak + 9][ar] = v2.y;  At[ak + 10][ar] = v2.z; At[ak + 11][ar] = v2.w;
      At[ak + 12][ar] = v3.x; At[ak + 13][ar] = v3.y; At[ak + 14][ar] = v3.z; At[ak + 15][ar] = v3.w;
    }
    {
      const float* p = W + (size_t)(kc + wr) * HID + wq;
      float4 u0 = *(const float4*)p, u1 = *(const float4*)(p + 4);
      float4 u2 = *(const float4*)(p + 8), u3 = *(const float4*)(p + 12);
      *(float4*)&Wt[wr][wq + 0] = u0;
      *(float4*)&Wt[wr][wq + 4] = u1;
      *(float4*)&Wt[wr][wq + 8] = u2;
      *(float4*)&Wt[wr][wq + 12] = u3;
    }
    __syncthreads();
#pragma unroll 4
    for (int k = 0; k < 32; ++k) {
      float a[8], b[8];
      *(float4*)&a[0] = *(const float4*)&At[k][tr * 8];
      *(float4*)&a[4] = *(const float4*)&At[k][tr * 8 + 4];
      *(float4*)&b[0] = *(const float4*)&Wt[k][tc * 4];
      *(float4*)&b[4] = *(const float4*)&Wt[k][64 + tc * 4];
#pragma unroll
      for (int i = 0; i < 8; ++i)
#pragma unroll
        for (int j = 0; j < 8; ++j) acc[i][j] = fmaf(a[i], b[j], acc[i][j]);
    }
  }

  const int c0 = tc * 4, c1 = 64 + tc * 4;
#pragma unroll
  for (int i = 0; i < 8; ++i) {
    int r = m0 + tr * 8 + i;
    if (r >= M) continue;
    float4 z0 = {acc[i][0], acc[i][1], acc[i][2], acc[i][3]};
    float4 z1 = {acc[i][4], acc[i][5], acc[i][6], acc[i][7]};
    if constexpr (EPI == 0) {
      float4 bb0 = *(const float4*)&bias[c0];
      float4 bb1 = *(const float4*)&bias[c1];
      z0.x = fmaxf(z0.x + bb0.x, 0.f); z0.y = fmaxf(z0.y + bb0.y, 0.f);
      z0.z = fmaxf(z0.z + bb0.z, 0.f); z0.w = fmaxf(z0.w + bb0.w, 0.f);
      z1.x = fmaxf(z1.x + bb1.x, 0.f); z1.y = fmaxf(z1.y + bb1.y, 0.f);
      z1.z = fmaxf(z1.z + bb1.z, 0.f); z1.w = fmaxf(z1.w + bb1.w, 0.f);
      *(float4*)&C32[(size_t)r * HID + c0] = z0;
      *(float4*)&C32[(size_t)r * HID + c1] = z1;
    } else {
      const float ob = 1.f - beta;
      float4 h0 = *(const float4*)&A[(size_t)r * K + c0];
      float4 h1 = *(const float4*)&A[(size_t)r * K + c1];
      z0.x = fmaxf(ob * h0.x + beta * z0.x, 0.f); z0.y = fmaxf(ob * h0.y + beta * z0.y, 0.f);
      z0.z = fmaxf(ob * h0.z + beta * z0.z, 0.f); z0.w = fmaxf(ob * h0.w + beta * z0.w, 0.f);
      z1.x = fmaxf(ob * h1.x + beta * z1.x, 0.f); z1.y = fmaxf(ob * h1.y + beta * z1.y, 0.f);
      z1.z = fmaxf(ob * h1.z + beta * z1.z, 0.f); z1.w = fmaxf(ob * h1.w + beta * z1.w, 0.f);
    }
    ushort4 s0 = {f2bf(z0.x), f2bf(z0.y), f2bf(z0.z), f2bf(z0.w)};
    ushort4 s1 = {f2bf(z1.x), f2bf(z1.y), f2bf(z1.z), f2bf(z1.w)};
    *(ushort4*)&C16[(size_t)r * HID + c0] = s0;
    *(ushort4*)&C16[(size_t)r * HID + c1] = s1;
  }
}

// ---------------- aggregation: hc = 0.5*(A_hat @ h16) + 0.5*x0 ----------------
// 256 threads = 4 waves, one node per wave. Wave: 4 edge-slots x 16 lanes x 8 bf16 ch.
static __global__ __launch_bounds__(256) void k_agg(
    const unsigned short* __restrict__ h16, const float* __restrict__ x0,
    const float* __restrict__ dinv, const int* __restrict__ offs,
    const int2* __restrict__ edata, float* __restrict__ hc) {
  int wid = threadIdx.x >> 6;
  int n = blockIdx.x * 4 + wid;
  if (n >= NN) return;
  int lane = threadIdx.x & 63;
  int cg = (lane & 15) * 8;  // channel group base
  int slot = lane >> 4;      // 0..3

  int b = offs[n], e = offs[n + 1];
  float acc[8];
#pragma unroll
  for (int j = 0; j < 8; ++j) acc[j] = 0.f;

#define ACC8(PTR, W)                                                          \
  {                                                                           \
    const uint4 v = *(const uint4*)(PTR);                                     \
    acc[0] = fmaf((W), __uint_as_float(v.x << 16), acc[0]);                   \
    acc[1] = fmaf((W), __uint_as_float(v.x & 0xffff0000u), acc[1]);           \
    acc[2] = fmaf((W), __uint_as_float(v.y << 16), acc[2]);                   \
    acc[3] = fmaf((W), __uint_as_float(v.y & 0xffff0000u), acc[3]);           \
    acc[4] = fmaf((W), __uint_as_float(v.z << 16), acc[4]);                   \
    acc[5] = fmaf((W), __uint_as_float(v.z & 0xffff0000u), acc[5]);           \
    acc[6] = fmaf((W), __uint_as_float(v.w << 16), acc[6]);                   \
    acc[7] = fmaf((W), __uint_as_float(v.w & 0xffff0000u), acc[7]);           \
  }

  if (slot == 0) {  // self loop
    float dn = dinv[n];
    ACC8(h16 + (size_t)n * HID + cg, dn * dn);
  }
  for (int i = b + slot; i < e; i += 4) {
    int2 ed = edata[i];
    float w = __int_as_float(ed.y);
    ACC8(h16 + (size_t)ed.x * HID + cg, w);
  }
#undef ACC8

#pragma unroll
  for (int j = 0; j < 8; ++j) {
    acc[j] += __shfl_xor(acc[j], 16);
    acc[j] += __shfl_xor(acc[j], 32);
  }

  if (lane < 16) {
    size_t nc = (size_t)n * HID + cg;
    float4 xa = *(const float4*)(x0 + nc);
    float4 xb = *(const float4*)(x0 + nc + 4);
    float4 o0 = {0.5f * acc[0] + 0.5f * xa.x, 0.5f * acc[1] + 0.5f * xa.y,
                 0.5f * acc[2] + 0.5f * xa.z, 0.5f * acc[3] + 0.5f * xa.w};
    float4 o1 = {0.5f * acc[4] + 0.5f * xb.x, 0.5f * acc[5] + 0.5f * xb.y,
                 0.5f * acc[6] + 0.5f * xb.z, 0.5f * acc[7] + 0.5f * xb.w};
    *(float4*)(hc + nc) = o0;
    *(float4*)(hc + nc + 4) = o1;
  }
}

// ---------------- lin2 + log_softmax (wave per row, bf16 h) ----------------
static __global__ __launch_bounds__(256) void k_lin2(const unsigned short* __restrict__ h16,
                                                     const float* __restrict__ W2,
                                                     const float* __restrict__ b2,
                                                     float* __restrict__ out) {
  __shared__ float sW[HID * OUTC];  // 20 KB
  __shared__ float sh[4][HID];
  for (int i = threadIdx.x; i < HID * OUTC; i += 256) sW[i] = W2[i];
  int wid = threadIdx.x >> 6, lane = threadIdx.x & 63;
  int r = blockIdx.x * 4 + wid;
  bool valid = r < NN;
  if (valid) {
    unsigned u = *(const unsigned*)(h16 + (size_t)r * HID + lane * 2);
    sh[wid][lane * 2] = __uint_as_float(u << 16);
    sh[wid][lane * 2 + 1] = __uint_as_float(u & 0xffff0000u);
  }
  __syncthreads();
  if (!valid) return;
  float acc = (lane < OUTC) ? b2[lane] : -1e30f;
  if (lane < OUTC) {
#pragma unroll 8
    for (int k = 0; k < HID; ++k) acc = fmaf(sh[wid][k], sW[k * OUTC + lane], acc);
  }
  float m = acc;
  for (int d = 32; d; d >>= 1) m = fmaxf(m, __shfl_xor(m, d));
  float ex = (lane < OUTC) ? __expf(acc - m) : 0.f;
  float ssum = ex;
  for (int d = 32; d; d >>= 1) ssum += __shfl_xor(ssum, d);
  if (lane < OUTC) out[(size_t)r * OUTC + lane] = acc - m - logf(ssum);
}

// ---------------- host ----------------
extern "C" void kernel_launch(void* const* d_in, const int* in_sizes, int n_in,
                              void* d_out, int out_size, void* d_ws, size_t ws_size,
                              hipStream_t stream) {
  const float* x  = (const float*)d_in[0];
  const int*   ei = (const int*)d_in[1];
  const float* w1 = (const float*)d_in[2];
  const float* b1 = (const float*)d_in[3];
  const float* cw = (const float*)d_in[4];
  const float* w2 = (const float*)d_in[5];
  const float* b2 = (const float*)d_in[6];
  float* out = (float*)d_out;

  char* ws = (char*)d_ws;
  size_t o = 0;
  auto carve = [&](size_t bytes) {
    void* p = ws + o;
    o = (o + bytes + 255) & ~(size_t)255;
    return p;
  };
  int*   cnt    = (int*)carve((size_t)NN * 4);
  float* dinv   = (float*)carve((size_t)NN * 4);
  int*   offs   = (int*)carve((size_t)(NN + 1) * 4);
  int*   cursor = (int*)carve((size_t)NN * 4);
  int*   bsum   = (int*)carve(512 * 4);
  int2*  edata  = (int2*)carve((size_t)NE * 8);
  float* x0f    = (float*)carve((size_t)NN * HID * 4);
  float* hcb    = (float*)carve((size_t)NN * HID * 4);
  unsigned short* x016 = (unsigned short*)carve((size_t)NN * HID * 2);
  unsigned short* hb16 = (unsigned short*)carve((size_t)NN * HID * 2);
  (void)ws_size; (void)in_sizes; (void)n_in; (void)out_size;

  const int TB = 256;
  const int gN = (NN + TB - 1) / TB;  // 391
  const int gE = (NE + TB - 1) / TB;  // 6250

  k_zero<<<gN, TB, 0, stream>>>(cnt);
  k_hist<<<gE, TB, 0, stream>>>(ei, cnt);
  k_dinv<<<gN, TB, 0, stream>>>(cnt, dinv, offs);
  k_scan1<<<gN, TB, 0, stream>>>(cnt, bsum);
  k_scan2<<<1, 512, 0, stream>>>(bsum, gN);
  k_scan3<<<gN, TB, 0, stream>>>(cnt, bsum, offs, cursor);
  k_fill<<<gE, TB, 0, stream>>>(ei, dinv, cursor, edata);

  const int gG = (NN + 127) / 128;  // 782
  k_gemm<INCH, 0><<<gG, 256, 0, stream>>>(x, w1, b1, 0.f, x0f, x016, NN);

  const unsigned short* hin = x016;
  const int gA = (NN + 3) / 4;  // 25000
  for (int l = 0; l < NLAYERS; ++l) {
    float beta = logf(1.0f / (float)(l + 1) + 1.0f);
    k_agg<<<gA, 256, 0, stream>>>(hin, x0f, dinv, offs, edata, hcb);
    k_gemm<HID, 1><<<gG, 256, 0, stream>>>(hcb, cw + (size_t)l * HID * HID, nullptr, beta,
                                           nullptr, hb16, NN);
    hin = hb16;
  }
  k_lin2<<<gA, 256, 0, stream>>>(hb16, w2, b2, out);
}

// Round 3
// 1162.306 us; speedup vs baseline: 1.9159x; 1.2244x over previous
//
#include <hip/hip_runtime.h>
#include <math.h>

#define NN 100000
#define NE 1600000
#define HID 128
#define INCH 256
#define OUTC 40
#define NLAYERS 8

typedef __attribute__((ext_vector_type(8))) short bf16x8;
typedef __attribute__((ext_vector_type(4))) float f32x4;

static __device__ inline unsigned short f2bf(float f) {
  unsigned u = __float_as_uint(f);
  unsigned r = (u + 0x7fff + ((u >> 16) & 1)) >> 16;
  return (unsigned short)r;
}

// ---------------- preprocessing kernels ----------------

static __global__ void k_zero(int* __restrict__ cnt) {
  int i = blockIdx.x * 256 + threadIdx.x;
  if (i < NN) cnt[i] = 0;
}

static __global__ void k_hist(const int* __restrict__ ei, int* __restrict__ cnt) {
  int e = blockIdx.x * 256 + threadIdx.x;
  if (e < NE) atomicAdd(&cnt[ei[NE + e]], 1);
}

static __global__ void k_dinv(const int* __restrict__ cnt, float* __restrict__ dinv,
                              int* __restrict__ offs) {
  int i = blockIdx.x * 256 + threadIdx.x;
  if (i < NN) dinv[i] = rsqrtf((float)(cnt[i] + 1));  // +1 self loop; always > 0
  if (blockIdx.x == 0 && threadIdx.x == 0) offs[NN] = NE;
}

static __global__ void k_scan1(const int* __restrict__ cnt, int* __restrict__ bsum) {
  __shared__ int sd[256];
  int t = threadIdx.x;
  int gid = blockIdx.x * 256 + t;
  sd[t] = (gid < NN) ? cnt[gid] : 0;
  __syncthreads();
  for (int s = 128; s > 0; s >>= 1) {
    if (t < s) sd[t] += sd[t + s];
    __syncthreads();
  }
  if (t == 0) bsum[blockIdx.x] = sd[0];
}

static __global__ void k_scan2(int* __restrict__ bsum, int nb) {
  __shared__ int sd[512];
  int t = threadIdx.x;
  sd[t] = (t < nb) ? bsum[t] : 0;
  __syncthreads();
  for (int d = 1; d < 512; d <<= 1) {
    int v = (t >= d) ? sd[t - d] : 0;
    __syncthreads();
    sd[t] += v;
    __syncthreads();
  }
  if (t < nb) bsum[t] = sd[t];  // inclusive scan
}

static __global__ void k_scan3(const int* __restrict__ cnt, const int* __restrict__ bsum,
                               int* __restrict__ offs, int* __restrict__ cursor) {
  __shared__ int sd[256];
  int t = threadIdx.x;
  int gid = blockIdx.x * 256 + t;
  int v = (gid < NN) ? cnt[gid] : 0;
  sd[t] = v;
  __syncthreads();
  for (int d = 1; d < 256; d <<= 1) {
    int u = (t >= d) ? sd[t - d] : 0;
    __syncthreads();
    sd[t] += u;
    __syncthreads();
  }
  int base = (blockIdx.x > 0) ? bsum[blockIdx.x - 1] : 0;
  int excl = base + sd[t] - v;
  if (gid < NN) { offs[gid] = excl; cursor[gid] = excl; }
}

static __global__ void k_fill(const int* __restrict__ ei, const float* __restrict__ dinv,
                              int* __restrict__ cursor, int2* __restrict__ edata) {
  int e = blockIdx.x * 256 + threadIdx.x;
  if (e < NE) {
    int s = ei[e];        // row = source
    int d = ei[NE + e];   // col = target (aggregation)
    int pos = atomicAdd(&cursor[d], 1);
    edata[pos] = make_int2(s, __float_as_int(dinv[s] * dinv[d]));
  }
}

// ---------------- weight conversion: W[K][128] f32 -> Wt16[128][K] bf16 ----------------
static __global__ void k_cvtw(const float* __restrict__ W, unsigned short* __restrict__ Wt,
                              int K) {
  int idx = blockIdx.x * 256 + threadIdx.x;
  if (idx < K * HID) {
    int k = idx >> 7, n = idx & 127;
    Wt[(size_t)n * K + k] = f2bf(W[idx]);
  }
}

static __global__ void k_cvtw8(const float* __restrict__ W, unsigned short* __restrict__ Wt) {
  int idx = blockIdx.x * 256 + threadIdx.x;  // over 8*128*128
  if (idx < NLAYERS * HID * HID) {
    int l = idx >> 14, rem = idx & 16383;
    int k = rem >> 7, n = rem & 127;
    Wt[(size_t)l * HID * HID + n * HID + k] = f2bf(W[idx]);
  }
}

// ---------------- MFMA GEMM: C[M x 128] = epi(A[M x K] @ W[K x 128]) ----------------
// bf16 x bf16 -> f32 accum via v_mfma_f32_16x16x32_bf16. No LDS, no barriers:
// each wave holds all its B-fragments in registers (CT coltiles x K/32 ksteps).
// EPI 0: z = relu(acc + bias[col]); write C32 (f32) + C16 (bf16). A is f32 (A32).
// EPI 1: z = relu((1-beta)*hc32 + beta*acc); write C16 only. A is bf16 (A16).
template <int K, int CT, int EPI>
__global__ __launch_bounds__(256, 2) void k_mgemm(
    const unsigned short* __restrict__ A16, const float* __restrict__ A32,
    const unsigned short* __restrict__ Wt16, const float* __restrict__ bias,
    const float* __restrict__ hc32, float beta, float* __restrict__ C32,
    unsigned short* __restrict__ C16, int M) {
  constexpr int KS = K / 32;
  constexpr int CH = 8 / CT;          // 1: wave covers all 128 cols; 2: half
  constexpr int RPB = 64 * (4 / CH);  // rows per block
  const int lane = threadIdx.x & 63;
  const int wid = threadIdx.x >> 6;
  const int rowblk = (CH == 1) ? wid : (wid >> 1);
  const int colbase = (CH == 1) ? 0 : ((wid & 1) << 6);
  const int j = lane & 15, g = lane >> 4;

  // B fragments: lane j -> col (colbase+16c+j), k-octet g -> k = 32s+8g..+7
  bf16x8 bfrag[CT][KS];
#pragma unroll
  for (int c = 0; c < CT; ++c)
#pragma unroll
    for (int s = 0; s < KS; ++s)
      bfrag[c][s] =
          *(const bf16x8*)(Wt16 + (size_t)(colbase + 16 * c + j) * K + 32 * s + 8 * g);

  const int wrow0 = blockIdx.x * RPB + rowblk * 64;
  const f32x4 zero = {0.f, 0.f, 0.f, 0.f};
#pragma unroll 1
  for (int t = 0; t < 4; ++t) {
    const int row0 = wrow0 + 16 * t;
    int rl = row0 + j;
    if (rl >= M) rl = M - 1;  // clamp loads; stores guarded below
    bf16x8 af[KS];
    if constexpr (EPI == 0) {
#pragma unroll
      for (int s = 0; s < KS; ++s) {
        const float* p = A32 + (size_t)rl * K + 32 * s + 8 * g;
        float4 u0 = *(const float4*)p;
        float4 u1 = *(const float4*)(p + 4);
        bf16x8 v;
        v[0] = (short)f2bf(u0.x); v[1] = (short)f2bf(u0.y);
        v[2] = (short)f2bf(u0.z); v[3] = (short)f2bf(u0.w);
        v[4] = (short)f2bf(u1.x); v[5] = (short)f2bf(u1.y);
        v[6] = (short)f2bf(u1.z); v[7] = (short)f2bf(u1.w);
        af[s] = v;
      }
    } else {
#pragma unroll
      for (int s = 0; s < KS; ++s)
        af[s] = *(const bf16x8*)(A16 + (size_t)rl * K + 32 * s + 8 * g);
    }
    f32x4 acc[CT];
#pragma unroll
    for (int c = 0; c < CT; ++c) acc[c] = zero;
#pragma unroll
    for (int s = 0; s < KS; ++s)
#pragma unroll
      for (int c = 0; c < CT; ++c)
        acc[c] = __builtin_amdgcn_mfma_f32_16x16x32_bf16(af[s], bfrag[c][s], acc[c], 0, 0, 0);

    // epilogue: C/D layout col=lane&15, row=(lane>>4)*4+reg
#pragma unroll
    for (int i = 0; i < 4; ++i) {
      const int rr = row0 + 4 * g + i;
      if (rr >= M) continue;
#pragma unroll
      for (int c = 0; c < CT; ++c) {
        const int col = colbase + 16 * c + j;
        float z = acc[c][i];
        if constexpr (EPI == 0) {
          z = fmaxf(z + bias[col], 0.f);
          C32[(size_t)rr * HID + col] = z;
        } else {
          z = fmaxf(fmaf(beta, z, (1.f - beta) * hc32[(size_t)rr * HID + col]), 0.f);
        }
        C16[(size_t)rr * HID + col] = f2bf(z);
      }
    }
  }
}

// ---------------- aggregation: hc = 0.5*(A_hat @ h16) + 0.5*x0 ----------------
// 256 threads = 4 waves, one node per wave. Wave: 4 edge-slots x 16 lanes x 8 bf16 ch.
// Writes hc in f32 (skip path) AND bf16 (MFMA A operand).
static __global__ __launch_bounds__(256) void k_agg(
    const unsigned short* __restrict__ h16, const float* __restrict__ x0,
    const float* __restrict__ dinv, const int* __restrict__ offs,
    const int2* __restrict__ edata, float* __restrict__ hc,
    unsigned short* __restrict__ hc16) {
  int wid = threadIdx.x >> 6;
  int n = blockIdx.x * 4 + wid;
  if (n >= NN) return;
  int lane = threadIdx.x & 63;
  int cg = (lane & 15) * 8;  // channel group base
  int slot = lane >> 4;      // 0..3

  int b = offs[n], e = offs[n + 1];
  float acc[8];
#pragma unroll
  for (int j = 0; j < 8; ++j) acc[j] = 0.f;

#define ACC8(PTR, W)                                                          \
  {                                                                           \
    const uint4 v = *(const uint4*)(PTR);                                     \
    acc[0] = fmaf((W), __uint_as_float(v.x << 16), acc[0]);                   \
    acc[1] = fmaf((W), __uint_as_float(v.x & 0xffff0000u), acc[1]);           \
    acc[2] = fmaf((W), __uint_as_float(v.y << 16), acc[2]);                   \
    acc[3] = fmaf((W), __uint_as_float(v.y & 0xffff0000u), acc[3]);           \
    acc[4] = fmaf((W), __uint_as_float(v.z << 16), acc[4]);                   \
    acc[5] = fmaf((W), __uint_as_float(v.z & 0xffff0000u), acc[5]);           \
    acc[6] = fmaf((W), __uint_as_float(v.w << 16), acc[6]);                   \
    acc[7] = fmaf((W), __uint_as_float(v.w & 0xffff0000u), acc[7]);           \
  }

  if (slot == 0) {  // self loop
    float dn = dinv[n];
    ACC8(h16 + (size_t)n * HID + cg, dn * dn);
  }
  for (int i = b + slot; i < e; i += 4) {
    int2 ed = edata[i];
    float w = __int_as_float(ed.y);
    ACC8(h16 + (size_t)ed.x * HID + cg, w);
  }
#undef ACC8

#pragma unroll
  for (int j = 0; j < 8; ++j) {
    acc[j] += __shfl_xor(acc[j], 16);
    acc[j] += __shfl_xor(acc[j], 32);
  }

  if (lane < 16) {
    size_t nc = (size_t)n * HID + cg;
    float4 xa = *(const float4*)(x0 + nc);
    float4 xb = *(const float4*)(x0 + nc + 4);
    float4 o0 = {0.5f * acc[0] + 0.5f * xa.x, 0.5f * acc[1] + 0.5f * xa.y,
                 0.5f * acc[2] + 0.5f * xa.z, 0.5f * acc[3] + 0.5f * xa.w};
    float4 o1 = {0.5f * acc[4] + 0.5f * xb.x, 0.5f * acc[5] + 0.5f * xb.y,
                 0.5f * acc[6] + 0.5f * xb.z, 0.5f * acc[7] + 0.5f * xb.w};
    *(float4*)(hc + nc) = o0;
    *(float4*)(hc + nc + 4) = o1;
    ushort4 q0 = {f2bf(o0.x), f2bf(o0.y), f2bf(o0.z), f2bf(o0.w)};
    ushort4 q1 = {f2bf(o1.x), f2bf(o1.y), f2bf(o1.z), f2bf(o1.w)};
    *(ushort4*)(hc16 + nc) = q0;
    *(ushort4*)(hc16 + nc + 4) = q1;
  }
}

// ---------------- lin2 + log_softmax (wave per row, bf16 h) ----------------
static __global__ __launch_bounds__(256) void k_lin2(const unsigned short* __restrict__ h16,
                                                     const float* __restrict__ W2,
                                                     const float* __restrict__ b2,
                                                     float* __restrict__ out) {
  __shared__ float sW[HID * OUTC];  // 20 KB
  __shared__ float sh[4][HID];
  for (int i = threadIdx.x; i < HID * OUTC; i += 256) sW[i] = W2[i];
  int wid = threadIdx.x >> 6, lane = threadIdx.x & 63;
  int r = blockIdx.x * 4 + wid;
  bool valid = r < NN;
  if (valid) {
    unsigned u = *(const unsigned*)(h16 + (size_t)r * HID + lane * 2);
    sh[wid][lane * 2] = __uint_as_float(u << 16);
    sh[wid][lane * 2 + 1] = __uint_as_float(u & 0xffff0000u);
  }
  __syncthreads();
  if (!valid) return;
  float acc = (lane < OUTC) ? b2[lane] : -1e30f;
  if (lane < OUTC) {
#pragma unroll 8
    for (int k = 0; k < HID; ++k) acc = fmaf(sh[wid][k], sW[k * OUTC + lane], acc);
  }
  float m = acc;
  for (int d = 32; d; d >>= 1) m = fmaxf(m, __shfl_xor(m, d));
  float ex = (lane < OUTC) ? __expf(acc - m) : 0.f;
  float ssum = ex;
  for (int d = 32; d; d >>= 1) ssum += __shfl_xor(ssum, d);
  if (lane < OUTC) out[(size_t)r * OUTC + lane] = acc - m - logf(ssum);
}

// ---------------- host ----------------
extern "C" void kernel_launch(void* const* d_in, const int* in_sizes, int n_in,
                              void* d_out, int out_size, void* d_ws, size_t ws_size,
                              hipStream_t stream) {
  const float* x  = (const float*)d_in[0];
  const int*   ei = (const int*)d_in[1];
  const float* w1 = (const float*)d_in[2];
  const float* b1 = (const float*)d_in[3];
  const float* cw = (const float*)d_in[4];
  const float* w2 = (const float*)d_in[5];
  const float* b2 = (const float*)d_in[6];
  float* out = (float*)d_out;

  char* ws = (char*)d_ws;
  size_t o = 0;
  auto carve = [&](size_t bytes) {
    void* p = ws + o;
    o = (o + bytes + 255) & ~(size_t)255;
    return p;
  };
  int*   cnt    = (int*)carve((size_t)NN * 4);
  float* dinv   = (float*)carve((size_t)NN * 4);
  int*   offs   = (int*)carve((size_t)(NN + 1) * 4);
  int*   cursor = (int*)carve((size_t)NN * 4);
  int*   bsum   = (int*)carve(512 * 4);
  int2*  edata  = (int2*)carve((size_t)NE * 8);
  float* x0f    = (float*)carve((size_t)NN * HID * 4);
  float* hcb    = (float*)carve((size_t)NN * HID * 4);
  unsigned short* x016  = (unsigned short*)carve((size_t)NN * HID * 2);
  unsigned short* hb16  = (unsigned short*)carve((size_t)NN * HID * 2);
  unsigned short* hcb16 = (unsigned short*)carve((size_t)NN * HID * 2);
  unsigned short* wt1   = (unsigned short*)carve((size_t)INCH * HID * 2);
  unsigned short* wtl   = (unsigned short*)carve((size_t)NLAYERS * HID * HID * 2);
  (void)ws_size; (void)in_sizes; (void)n_in; (void)out_size;

  const int TB = 256;
  const int gN = (NN + TB - 1) / TB;  // 391
  const int gE = (NE + TB - 1) / TB;  // 6250

  k_zero<<<gN, TB, 0, stream>>>(cnt);
  k_hist<<<gE, TB, 0, stream>>>(ei, cnt);
  k_dinv<<<gN, TB, 0, stream>>>(cnt, dinv, offs);
  k_scan1<<<gN, TB, 0, stream>>>(cnt, bsum);
  k_scan2<<<1, 512, 0, stream>>>(bsum, gN);
  k_scan3<<<gN, TB, 0, stream>>>(cnt, bsum, offs, cursor);
  k_fill<<<gE, TB, 0, stream>>>(ei, dinv, cursor, edata);

  k_cvtw<<<(INCH * HID + 255) / 256, 256, 0, stream>>>(w1, wt1, INCH);
  k_cvtw8<<<(NLAYERS * HID * HID + 255) / 256, 256, 0, stream>>>(cw, wtl);

  // lin1: x(f32) @ W1 -> x0f (f32) + x016 (bf16).  CT=4 -> 128 rows/block
  k_mgemm<INCH, 4, 0><<<(NN + 127) / 128, 256, 0, stream>>>(
      nullptr, x, wt1, b1, nullptr, 0.f, x0f, x016, NN);

  const unsigned short* hin = x016;
  const int gA = (NN + 3) / 4;  // 25000
  for (int l = 0; l < NLAYERS; ++l) {
    float beta = logf(1.0f / (float)(l + 1) + 1.0f);
    k_agg<<<gA, 256, 0, stream>>>(hin, x0f, dinv, offs, edata, hcb, hcb16);
    // layer GEMM: hc(bf16) @ Wl -> hb16 (bf16).  CT=8 -> 256 rows/block
    k_mgemm<HID, 8, 1><<<(NN + 255) / 256, 256, 0, stream>>>(
        hcb16, nullptr, wtl + (size_t)l * HID * HID, nullptr, hcb, beta, nullptr, hb16, NN);
    hin = hb16;
  }
  k_lin2<<<gA, 256, 0, stream>>>(hb16, w2, b2, out);
}

// Round 4
// 1099.862 us; speedup vs baseline: 2.0246x; 1.0568x over previous
//
#include <hip/hip_runtime.h>
#include <math.h>

#define NN 100000
#define NE 1600000
#define HID 128
#define INCH 256
#define OUTC 40
#define NLAYERS 8

typedef __attribute__((ext_vector_type(8))) short bf16x8;
typedef __attribute__((ext_vector_type(4))) float f32x4;

static __device__ inline unsigned short f2bf(float f) {
  unsigned u = __float_as_uint(f);
  unsigned r = (u + 0x7fff + ((u >> 16) & 1)) >> 16;
  return (unsigned short)r;
}

// ---------------- preprocessing kernels ----------------

static __global__ void k_zero(int* __restrict__ cnt) {
  int i = blockIdx.x * 256 + threadIdx.x;
  if (i < NN) cnt[i] = 0;
}

static __global__ void k_hist(const int* __restrict__ ei, int* __restrict__ cnt) {
  int e = blockIdx.x * 256 + threadIdx.x;
  if (e < NE) atomicAdd(&cnt[ei[NE + e]], 1);
}

static __global__ void k_dinv(const int* __restrict__ cnt, float* __restrict__ dinv,
                              int* __restrict__ offs) {
  int i = blockIdx.x * 256 + threadIdx.x;
  if (i < NN) dinv[i] = rsqrtf((float)(cnt[i] + 1));  // +1 self loop; always > 0
  if (blockIdx.x == 0 && threadIdx.x == 0) offs[NN] = NE;
}

static __global__ void k_scan1(const int* __restrict__ cnt, int* __restrict__ bsum) {
  __shared__ int sd[256];
  int t = threadIdx.x;
  int gid = blockIdx.x * 256 + t;
  sd[t] = (gid < NN) ? cnt[gid] : 0;
  __syncthreads();
  for (int s = 128; s > 0; s >>= 1) {
    if (t < s) sd[t] += sd[t + s];
    __syncthreads();
  }
  if (t == 0) bsum[blockIdx.x] = sd[0];
}

static __global__ void k_scan2(int* __restrict__ bsum, int nb) {
  __shared__ int sd[512];
  int t = threadIdx.x;
  sd[t] = (t < nb) ? bsum[t] : 0;
  __syncthreads();
  for (int d = 1; d < 512; d <<= 1) {
    int v = (t >= d) ? sd[t - d] : 0;
    __syncthreads();
    sd[t] += v;
    __syncthreads();
  }
  if (t < nb) bsum[t] = sd[t];  // inclusive scan
}

static __global__ void k_scan3(const int* __restrict__ cnt, const int* __restrict__ bsum,
                               int* __restrict__ offs, int* __restrict__ cursor) {
  __shared__ int sd[256];
  int t = threadIdx.x;
  int gid = blockIdx.x * 256 + t;
  int v = (gid < NN) ? cnt[gid] : 0;
  sd[t] = v;
  __syncthreads();
  for (int d = 1; d < 256; d <<= 1) {
    int u = (t >= d) ? sd[t - d] : 0;
    __syncthreads();
    sd[t] += u;
    __syncthreads();
  }
  int base = (blockIdx.x > 0) ? bsum[blockIdx.x - 1] : 0;
  int excl = base + sd[t] - v;
  if (gid < NN) { offs[gid] = excl; cursor[gid] = excl; }
}

static __global__ void k_fill(const int* __restrict__ ei, const float* __restrict__ dinv,
                              int* __restrict__ cursor, int2* __restrict__ edata) {
  int e = blockIdx.x * 256 + threadIdx.x;
  if (e < NE) {
    int s = ei[e];        // row = source
    int d = ei[NE + e];   // col = target (aggregation)
    int pos = atomicAdd(&cursor[d], 1);
    edata[pos] = make_int2(s, __float_as_int(dinv[s] * dinv[d]));
  }
}

// ---------------- weight conversion ----------------
static __global__ void k_cvtw(const float* __restrict__ W, unsigned short* __restrict__ Wt,
                              int K) {
  int idx = blockIdx.x * 256 + threadIdx.x;
  if (idx < K * HID) {
    int k = idx >> 7, n = idx & 127;
    Wt[(size_t)n * K + k] = f2bf(W[idx]);
  }
}

static __global__ void k_cvtw8(const float* __restrict__ W, unsigned short* __restrict__ Wt) {
  int idx = blockIdx.x * 256 + threadIdx.x;  // over 8*128*128
  if (idx < NLAYERS * HID * HID) {
    int l = idx >> 14, rem = idx & 16383;
    int k = rem >> 7, n = rem & 127;
    Wt[(size_t)l * HID * HID + n * HID + k] = f2bf(W[idx]);
  }
}

// W2[128][40] f32 -> Wt2[48][128] bf16 (transposed, zero-padded cols 40..47)
static __global__ void k_cvtw2(const float* __restrict__ W2, unsigned short* __restrict__ Wt2) {
  int idx = blockIdx.x * 256 + threadIdx.x;
  if (idx < 48 * HID) {
    int n = idx >> 7, k = idx & 127;
    Wt2[idx] = (n < OUTC) ? f2bf(W2[(size_t)k * OUTC + n]) : 0;
  }
}

// ---------------- MFMA GEMM: C[M x 128] = epi(A[M x K] @ W[K x 128]) ----------------
// bf16 x bf16 -> f32 accum via v_mfma_f32_16x16x32_bf16. No LDS, no barriers:
// each wave holds all its B-fragments in registers (CT coltiles x K/32 ksteps).
// EPI 0: z = relu(acc + bias[col]); write C32 (f32) + C16 (bf16). A is f32 (A32).
// EPI 1: z = relu((1-beta)*hc32 + beta*acc); write C16 only. A is bf16 (A16).
template <int K, int CT, int EPI>
__global__ __launch_bounds__(256, 2) void k_mgemm(
    const unsigned short* __restrict__ A16, const float* __restrict__ A32,
    const unsigned short* __restrict__ Wt16, const float* __restrict__ bias,
    const float* __restrict__ hc32, float beta, float* __restrict__ C32,
    unsigned short* __restrict__ C16, int M) {
  constexpr int KS = K / 32;
  constexpr int CH = 8 / CT;          // 1: wave covers all 128 cols; 2: half
  constexpr int RPB = 64 * (4 / CH);  // rows per block
  const int lane = threadIdx.x & 63;
  const int wid = threadIdx.x >> 6;
  const int rowblk = (CH == 1) ? wid : (wid >> 1);
  const int colbase = (CH == 1) ? 0 : ((wid & 1) << 6);
  const int j = lane & 15, g = lane >> 4;

  // B fragments: lane j -> col (colbase+16c+j), k-octet g -> k = 32s+8g..+7
  bf16x8 bfrag[CT][KS];
#pragma unroll
  for (int c = 0; c < CT; ++c)
#pragma unroll
    for (int s = 0; s < KS; ++s)
      bfrag[c][s] =
          *(const bf16x8*)(Wt16 + (size_t)(colbase + 16 * c + j) * K + 32 * s + 8 * g);

  const int wrow0 = blockIdx.x * RPB + rowblk * 64;
  const f32x4 zero = {0.f, 0.f, 0.f, 0.f};
#pragma unroll 1
  for (int t = 0; t < 4; ++t) {
    const int row0 = wrow0 + 16 * t;
    int rl = row0 + j;
    if (rl >= M) rl = M - 1;  // clamp loads; stores guarded below
    bf16x8 af[KS];
    if constexpr (EPI == 0) {
#pragma unroll
      for (int s = 0; s < KS; ++s) {
        const float* p = A32 + (size_t)rl * K + 32 * s + 8 * g;
        float4 u0 = *(const float4*)p;
        float4 u1 = *(const float4*)(p + 4);
        bf16x8 v;
        v[0] = (short)f2bf(u0.x); v[1] = (short)f2bf(u0.y);
        v[2] = (short)f2bf(u0.z); v[3] = (short)f2bf(u0.w);
        v[4] = (short)f2bf(u1.x); v[5] = (short)f2bf(u1.y);
        v[6] = (short)f2bf(u1.z); v[7] = (short)f2bf(u1.w);
        af[s] = v;
      }
    } else {
#pragma unroll
      for (int s = 0; s < KS; ++s)
        af[s] = *(const bf16x8*)(A16 + (size_t)rl * K + 32 * s + 8 * g);
    }
    f32x4 acc[CT];
#pragma unroll
    for (int c = 0; c < CT; ++c) acc[c] = zero;
#pragma unroll
    for (int s = 0; s < KS; ++s)
#pragma unroll
      for (int c = 0; c < CT; ++c)
        acc[c] = __builtin_amdgcn_mfma_f32_16x16x32_bf16(af[s], bfrag[c][s], acc[c], 0, 0, 0);

    // epilogue: C/D layout col=lane&15, row=(lane>>4)*4+reg
#pragma unroll
    for (int i = 0; i < 4; ++i) {
      const int rr = row0 + 4 * g + i;
      if (rr >= M) continue;
#pragma unroll
      for (int c = 0; c < CT; ++c) {
        const int col = colbase + 16 * c + j;
        float z = acc[c][i];
        if constexpr (EPI == 0) {
          z = fmaxf(z + bias[col], 0.f);
          C32[(size_t)rr * HID + col] = z;
        } else {
          z = fmaxf(fmaf(beta, z, (1.f - beta) * hc32[(size_t)rr * HID + col]), 0.f);
        }
        C16[(size_t)rr * HID + col] = f2bf(z);
      }
    }
  }
}

// ---------------- fused lin2 + log_softmax via MFMA ----------------
// out[M x 40] = log_softmax(h16 @ W2 + b2). W2 padded to 48 cols (CT=3).
// Row-wise max/sum via shfl_xor within the 16-lane col group.
static __global__ __launch_bounds__(256) void k_mlin2(
    const unsigned short* __restrict__ h16, const unsigned short* __restrict__ Wt2,
    const float* __restrict__ b2, float* __restrict__ out) {
  const int lane = threadIdx.x & 63;
  const int wid = threadIdx.x >> 6;
  const int j = lane & 15, g = lane >> 4;

  bf16x8 bfrag[3][4];
#pragma unroll
  for (int c = 0; c < 3; ++c)
#pragma unroll
    for (int s = 0; s < 4; ++s)
      bfrag[c][s] = *(const bf16x8*)(Wt2 + (size_t)(16 * c + j) * HID + 32 * s + 8 * g);

  float bb[3];
#pragma unroll
  for (int c = 0; c < 3; ++c) {
    int col = 16 * c + j;
    bb[c] = (col < OUTC) ? b2[col] : -1e30f;
  }

  const int wrow0 = blockIdx.x * 256 + wid * 64;
  const f32x4 zero = {0.f, 0.f, 0.f, 0.f};
#pragma unroll 1
  for (int t = 0; t < 4; ++t) {
    const int row0 = wrow0 + 16 * t;
    int rl = row0 + j;
    if (rl >= NN) rl = NN - 1;
    bf16x8 af[4];
#pragma unroll
    for (int s = 0; s < 4; ++s)
      af[s] = *(const bf16x8*)(h16 + (size_t)rl * HID + 32 * s + 8 * g);
    f32x4 acc[3] = {zero, zero, zero};
#pragma unroll
    for (int s = 0; s < 4; ++s)
#pragma unroll
      for (int c = 0; c < 3; ++c)
        acc[c] = __builtin_amdgcn_mfma_f32_16x16x32_bf16(af[s], bfrag[c][s], acc[c], 0, 0, 0);

#pragma unroll
    for (int i = 0; i < 4; ++i) {
      const int rr = row0 + 4 * g + i;
      float z0 = acc[0][i] + bb[0];
      float z1 = acc[1][i] + bb[1];
      float z2 = acc[2][i] + bb[2];
      float m = fmaxf(fmaxf(z0, z1), z2);
      m = fmaxf(m, __shfl_xor(m, 1));
      m = fmaxf(m, __shfl_xor(m, 2));
      m = fmaxf(m, __shfl_xor(m, 4));
      m = fmaxf(m, __shfl_xor(m, 8));
      float sum = __expf(z0 - m) + __expf(z1 - m) + __expf(z2 - m);
      sum += __shfl_xor(sum, 1);
      sum += __shfl_xor(sum, 2);
      sum += __shfl_xor(sum, 4);
      sum += __shfl_xor(sum, 8);
      float ls = m + logf(sum);
      if (rr < NN) {
        out[(size_t)rr * OUTC + j] = z0 - ls;
        out[(size_t)rr * OUTC + 16 + j] = z1 - ls;
        if (j < 8) out[(size_t)rr * OUTC + 32 + j] = z2 - ls;
      }
    }
  }
}

// ---------------- aggregation: hc = 0.5*(A_hat @ h16) + 0.5*x0 ----------------
// 256 threads = 4 waves, one node per wave. Wave: 4 edge-slots x 16 lanes x 8 bf16 ch.
// Writes hc in f32 (skip path) AND bf16 (MFMA A operand).
static __global__ __launch_bounds__(256) void k_agg(
    const unsigned short* __restrict__ h16, const float* __restrict__ x0,
    const float* __restrict__ dinv, const int* __restrict__ offs,
    const int2* __restrict__ edata, float* __restrict__ hc,
    unsigned short* __restrict__ hc16) {
  int wid = threadIdx.x >> 6;
  int n = blockIdx.x * 4 + wid;
  if (n >= NN) return;
  int lane = threadIdx.x & 63;
  int cg = (lane & 15) * 8;  // channel group base
  int slot = lane >> 4;      // 0..3

  int b = offs[n], e = offs[n + 1];
  float acc[8];
#pragma unroll
  for (int j = 0; j < 8; ++j) acc[j] = 0.f;

#define ACC8(PTR, W)                                                          \
  {                                                                           \
    const uint4 v = *(const uint4*)(PTR);                                     \
    acc[0] = fmaf((W), __uint_as_float(v.x << 16), acc[0]);                   \
    acc[1] = fmaf((W), __uint_as_float(v.x & 0xffff0000u), acc[1]);           \
    acc[2] = fmaf((W), __uint_as_float(v.y << 16), acc[2]);                   \
    acc[3] = fmaf((W), __uint_as_float(v.y & 0xffff0000u), acc[3]);           \
    acc[4] = fmaf((W), __uint_as_float(v.z << 16), acc[4]);                   \
    acc[5] = fmaf((W), __uint_as_float(v.z & 0xffff0000u), acc[5]);           \
    acc[6] = fmaf((W), __uint_as_float(v.w << 16), acc[6]);                   \
    acc[7] = fmaf((W), __uint_as_float(v.w & 0xffff0000u), acc[7]);           \
  }

  if (slot == 0) {  // self loop
    float dn = dinv[n];
    ACC8(h16 + (size_t)n * HID + cg, dn * dn);
  }
  for (int i = b + slot; i < e; i += 4) {
    int2 ed = edata[i];
    float w = __int_as_float(ed.y);
    ACC8(h16 + (size_t)ed.x * HID + cg, w);
  }
#undef ACC8

#pragma unroll
  for (int j = 0; j < 8; ++j) {
    acc[j] += __shfl_xor(acc[j], 16);
    acc[j] += __shfl_xor(acc[j], 32);
  }

  if (lane < 16) {
    size_t nc = (size_t)n * HID + cg;
    float4 xa = *(const float4*)(x0 + nc);
    float4 xb = *(const float4*)(x0 + nc + 4);
    float4 o0 = {0.5f * acc[0] + 0.5f * xa.x, 0.5f * acc[1] + 0.5f * xa.y,
                 0.5f * acc[2] + 0.5f * xa.z, 0.5f * acc[3] + 0.5f * xa.w};
    float4 o1 = {0.5f * acc[4] + 0.5f * xb.x, 0.5f * acc[5] + 0.5f * xb.y,
                 0.5f * acc[6] + 0.5f * xb.z, 0.5f * acc[7] + 0.5f * xb.w};
    *(float4*)(hc + nc) = o0;
    *(float4*)(hc + nc + 4) = o1;
    ushort4 q0 = {f2bf(o0.x), f2bf(o0.y), f2bf(o0.z), f2bf(o0.w)};
    ushort4 q1 = {f2bf(o1.x), f2bf(o1.y), f2bf(o1.z), f2bf(o1.w)};
    *(ushort4*)(hc16 + nc) = q0;
    *(ushort4*)(hc16 + nc + 4) = q1;
  }
}

// ---------------- host ----------------
extern "C" void kernel_launch(void* const* d_in, const int* in_sizes, int n_in,
                              void* d_out, int out_size, void* d_ws, size_t ws_size,
                              hipStream_t stream) {
  const float* x  = (const float*)d_in[0];
  const int*   ei = (const int*)d_in[1];
  const float* w1 = (const float*)d_in[2];
  const float* b1 = (const float*)d_in[3];
  const float* cw = (const float*)d_in[4];
  const float* w2 = (const float*)d_in[5];
  const float* b2 = (const float*)d_in[6];
  float* out = (float*)d_out;

  char* ws = (char*)d_ws;
  size_t o = 0;
  auto carve = [&](size_t bytes) {
    void* p = ws + o;
    o = (o + bytes + 255) & ~(size_t)255;
    return p;
  };
  int*   cnt    = (int*)carve((size_t)NN * 4);
  float* dinv   = (float*)carve((size_t)NN * 4);
  int*   offs   = (int*)carve((size_t)(NN + 1) * 4);
  int*   cursor = (int*)carve((size_t)NN * 4);
  int*   bsum   = (int*)carve(512 * 4);
  int2*  edata  = (int2*)carve((size_t)NE * 8);
  float* x0f    = (float*)carve((size_t)NN * HID * 4);
  float* hcb    = (float*)carve((size_t)NN * HID * 4);
  unsigned short* x016  = (unsigned short*)carve((size_t)NN * HID * 2);
  unsigned short* hb16  = (unsigned short*)carve((size_t)NN * HID * 2);
  unsigned short* hcb16 = (unsigned short*)carve((size_t)NN * HID * 2);
  unsigned short* wt1   = (unsigned short*)carve((size_t)INCH * HID * 2);
  unsigned short* wtl   = (unsigned short*)carve((size_t)NLAYERS * HID * HID * 2);
  unsigned short* wt2   = (unsigned short*)carve((size_t)48 * HID * 2);
  (void)ws_size; (void)in_sizes; (void)n_in; (void)out_size;

  const int TB = 256;
  const int gN = (NN + TB - 1) / TB;  // 391
  const int gE = (NE + TB - 1) / TB;  // 6250

  k_zero<<<gN, TB, 0, stream>>>(cnt);
  k_hist<<<gE, TB, 0, stream>>>(ei, cnt);
  k_dinv<<<gN, TB, 0, stream>>>(cnt, dinv, offs);
  k_scan1<<<gN, TB, 0, stream>>>(cnt, bsum);
  k_scan2<<<1, 512, 0, stream>>>(bsum, gN);
  k_scan3<<<gN, TB, 0, stream>>>(cnt, bsum, offs, cursor);
  k_fill<<<gE, TB, 0, stream>>>(ei, dinv, cursor, edata);

  k_cvtw<<<(INCH * HID + 255) / 256, 256, 0, stream>>>(w1, wt1, INCH);
  k_cvtw8<<<(NLAYERS * HID * HID + 255) / 256, 256, 0, stream>>>(cw, wtl);
  k_cvtw2<<<(48 * HID + 255) / 256, 256, 0, stream>>>(w2, wt2);

  // lin1: x(f32) @ W1 -> x0f (f32) + x016 (bf16).  CT=4 -> 128 rows/block
  k_mgemm<INCH, 4, 0><<<(NN + 127) / 128, 256, 0, stream>>>(
      nullptr, x, wt1, b1, nullptr, 0.f, x0f, x016, NN);

  const unsigned short* hin = x016;
  const int gA = (NN + 3) / 4;  // 25000
  for (int l = 0; l < NLAYERS; ++l) {
    float beta = logf(1.0f / (float)(l + 1) + 1.0f);
    k_agg<<<gA, 256, 0, stream>>>(hin, x0f, dinv, offs, edata, hcb, hcb16);
    // layer GEMM: hc(bf16) @ Wl -> hb16 (bf16).  CT=4 -> 128 rows/block
    k_mgemm<HID, 4, 1><<<(NN + 127) / 128, 256, 0, stream>>>(
        hcb16, nullptr, wtl + (size_t)l * HID * HID, nullptr, hcb, beta, nullptr, hb16, NN);
    hin = hb16;
  }
  k_mlin2<<<(NN + 255) / 256, 256, 0, stream>>>(hb16, wt2, b2, out);
}

// Round 5
// 984.170 us; speedup vs baseline: 2.2627x; 1.1176x over previous
//
#include <hip/hip_runtime.h>
#include <math.h>

#define NN 100000
#define NE 1600000
#define HID 128
#define INCH 256
#define OUTC 40
#define NLAYERS 8

typedef __attribute__((ext_vector_type(8))) short bf16x8;
typedef __attribute__((ext_vector_type(4))) float f32x4;

static __device__ inline unsigned short f2bf(float f) {
  unsigned u = __float_as_uint(f);
  unsigned r = (u + 0x7fff + ((u >> 16) & 1)) >> 16;
  return (unsigned short)r;
}
static __device__ inline float bflo(unsigned u) { return __uint_as_float(u << 16); }
static __device__ inline float bfhi(unsigned u) { return __uint_as_float(u & 0xffff0000u); }

// ---------------- preprocessing kernels ----------------

static __global__ void k_zero(int* __restrict__ cnt) {
  int i = blockIdx.x * 256 + threadIdx.x;
  if (i < NN) cnt[i] = 0;
}

static __global__ void k_hist(const int* __restrict__ ei, int* __restrict__ cnt) {
  int e = blockIdx.x * 256 + threadIdx.x;
  if (e < NE) atomicAdd(&cnt[ei[NE + e]], 1);
}

static __global__ void k_dinv(const int* __restrict__ cnt, float* __restrict__ dinv,
                              int* __restrict__ offs) {
  int i = blockIdx.x * 256 + threadIdx.x;
  if (i < NN) dinv[i] = rsqrtf((float)(cnt[i] + 1));  // +1 self loop; always > 0
  if (blockIdx.x == 0 && threadIdx.x == 0) offs[NN] = NE;
}

static __global__ void k_scan1(const int* __restrict__ cnt, int* __restrict__ bsum) {
  __shared__ int sd[256];
  int t = threadIdx.x;
  int gid = blockIdx.x * 256 + t;
  sd[t] = (gid < NN) ? cnt[gid] : 0;
  __syncthreads();
  for (int s = 128; s > 0; s >>= 1) {
    if (t < s) sd[t] += sd[t + s];
    __syncthreads();
  }
  if (t == 0) bsum[blockIdx.x] = sd[0];
}

static __global__ void k_scan2(int* __restrict__ bsum, int nb) {
  __shared__ int sd[512];
  int t = threadIdx.x;
  sd[t] = (t < nb) ? bsum[t] : 0;
  __syncthreads();
  for (int d = 1; d < 512; d <<= 1) {
    int v = (t >= d) ? sd[t - d] : 0;
    __syncthreads();
    sd[t] += v;
    __syncthreads();
  }
  if (t < nb) bsum[t] = sd[t];  // inclusive scan
}

static __global__ void k_scan3(const int* __restrict__ cnt, const int* __restrict__ bsum,
                               int* __restrict__ offs, int* __restrict__ cursor) {
  __shared__ int sd[256];
  int t = threadIdx.x;
  int gid = blockIdx.x * 256 + t;
  int v = (gid < NN) ? cnt[gid] : 0;
  sd[t] = v;
  __syncthreads();
  for (int d = 1; d < 256; d <<= 1) {
    int u = (t >= d) ? sd[t - d] : 0;
    __syncthreads();
    sd[t] += u;
    __syncthreads();
  }
  int base = (blockIdx.x > 0) ? bsum[blockIdx.x - 1] : 0;
  int excl = base + sd[t] - v;
  if (gid < NN) { offs[gid] = excl; cursor[gid] = excl; }
}

static __global__ void k_fill(const int* __restrict__ ei, const float* __restrict__ dinv,
                              int* __restrict__ cursor, int2* __restrict__ edata) {
  int e = blockIdx.x * 256 + threadIdx.x;
  if (e < NE) {
    int s = ei[e];        // row = source
    int d = ei[NE + e];   // col = target (aggregation)
    int pos = atomicAdd(&cursor[d], 1);
    edata[pos] = make_int2(s, __float_as_int(dinv[s] * dinv[d]));
  }
}

// ---------------- weight conversion ----------------
static __global__ void k_cvtw(const float* __restrict__ W, unsigned short* __restrict__ Wt,
                              int K) {
  int idx = blockIdx.x * 256 + threadIdx.x;
  if (idx < K * HID) {
    int k = idx >> 7, n = idx & 127;
    Wt[(size_t)n * K + k] = f2bf(W[idx]);
  }
}

static __global__ void k_cvtw8(const float* __restrict__ W, unsigned short* __restrict__ Wt) {
  int idx = blockIdx.x * 256 + threadIdx.x;  // over 8*128*128
  if (idx < NLAYERS * HID * HID) {
    int l = idx >> 14, rem = idx & 16383;
    int k = rem >> 7, n = rem & 127;
    Wt[(size_t)l * HID * HID + n * HID + k] = f2bf(W[idx]);
  }
}

// W2[128][40] f32 -> Wt2[48][128] bf16 (transposed, zero-padded cols 40..47)
static __global__ void k_cvtw2(const float* __restrict__ W2, unsigned short* __restrict__ Wt2) {
  int idx = blockIdx.x * 256 + threadIdx.x;
  if (idx < 48 * HID) {
    int n = idx >> 7, k = idx & 127;
    Wt2[idx] = (n < OUTC) ? f2bf(W2[(size_t)k * OUTC + n]) : 0;
  }
}

// ---------------- lin1: C16[M x 128] = bf16(relu(A32[M x 256] @ W + bias)) ----------------
// CT=4, CH=2: wave covers 64 rows x 64 cols over 4 row-tiles.
__global__ __launch_bounds__(256, 2) void k_lin1(
    const float* __restrict__ A32, const unsigned short* __restrict__ Wt16,
    const float* __restrict__ bias, unsigned short* __restrict__ C16, int M) {
  constexpr int K = INCH, KS = K / 32, CT = 4;
  const int lane = threadIdx.x & 63;
  const int wid = threadIdx.x >> 6;
  const int rowblk = wid >> 1;
  const int colbase = (wid & 1) << 6;
  const int j = lane & 15, g = lane >> 4;

  bf16x8 bfrag[CT][KS];
#pragma unroll
  for (int c = 0; c < CT; ++c)
#pragma unroll
    for (int s = 0; s < KS; ++s)
      bfrag[c][s] =
          *(const bf16x8*)(Wt16 + (size_t)(colbase + 16 * c + j) * K + 32 * s + 8 * g);

  const int wrow0 = blockIdx.x * 128 + rowblk * 64;
  const f32x4 zero = {0.f, 0.f, 0.f, 0.f};
#pragma unroll 1
  for (int t = 0; t < 4; ++t) {
    const int row0 = wrow0 + 16 * t;
    int rl = row0 + j;
    if (rl >= M) rl = M - 1;
    bf16x8 af[KS];
#pragma unroll
    for (int s = 0; s < KS; ++s) {
      const float* p = A32 + (size_t)rl * K + 32 * s + 8 * g;
      float4 u0 = *(const float4*)p;
      float4 u1 = *(const float4*)(p + 4);
      bf16x8 v;
      v[0] = (short)f2bf(u0.x); v[1] = (short)f2bf(u0.y);
      v[2] = (short)f2bf(u0.z); v[3] = (short)f2bf(u0.w);
      v[4] = (short)f2bf(u1.x); v[5] = (short)f2bf(u1.y);
      v[6] = (short)f2bf(u1.z); v[7] = (short)f2bf(u1.w);
      af[s] = v;
    }
    f32x4 acc[CT];
#pragma unroll
    for (int c = 0; c < CT; ++c) acc[c] = zero;
#pragma unroll
    for (int s = 0; s < KS; ++s)
#pragma unroll
      for (int c = 0; c < CT; ++c)
        acc[c] = __builtin_amdgcn_mfma_f32_16x16x32_bf16(af[s], bfrag[c][s], acc[c], 0, 0, 0);

#pragma unroll
    for (int i = 0; i < 4; ++i) {
      const int rr = row0 + 4 * g + i;
      if (rr >= M) continue;
#pragma unroll
      for (int c = 0; c < CT; ++c) {
        const int col = colbase + 16 * c + j;
        float z = fmaxf(acc[c][i] + bias[col], 0.f);
        C16[(size_t)rr * HID + col] = f2bf(z);
      }
    }
  }
}

// ---------------- layer GEMM: C16 = bf16(relu((1-beta)*A16 + beta*(A16 @ W))) ----------------
// K=128, CT=4, CH=2. All 4 row-tiles' A-fragments hoisted for memory parallelism.
__global__ __launch_bounds__(256, 2) void k_mgemm1(
    const unsigned short* __restrict__ A16, const unsigned short* __restrict__ Wt16,
    float beta, unsigned short* __restrict__ C16, int M) {
  constexpr int KS = 4, CT = 4;
  const int lane = threadIdx.x & 63;
  const int wid = threadIdx.x >> 6;
  const int rowblk = wid >> 1;
  const int colbase = (wid & 1) << 6;
  const int j = lane & 15, g = lane >> 4;

  bf16x8 bfrag[CT][KS];
#pragma unroll
  for (int c = 0; c < CT; ++c)
#pragma unroll
    for (int s = 0; s < KS; ++s)
      bfrag[c][s] =
          *(const bf16x8*)(Wt16 + (size_t)(colbase + 16 * c + j) * HID + 32 * s + 8 * g);

  const int wrow0 = blockIdx.x * 128 + rowblk * 64;

  // hoist all A-fragment loads (16 x 16B in flight per lane)
  bf16x8 af[4][KS];
#pragma unroll
  for (int t = 0; t < 4; ++t) {
    int rl = wrow0 + 16 * t + j;
    if (rl >= M) rl = M - 1;
#pragma unroll
    for (int s = 0; s < KS; ++s)
      af[t][s] = *(const bf16x8*)(A16 + (size_t)rl * HID + 32 * s + 8 * g);
  }

  const f32x4 zero = {0.f, 0.f, 0.f, 0.f};
  const float ob = 1.f - beta;
#pragma unroll
  for (int t = 0; t < 4; ++t) {
    const int row0 = wrow0 + 16 * t;
    f32x4 acc[CT];
#pragma unroll
    for (int c = 0; c < CT; ++c) acc[c] = zero;
#pragma unroll
    for (int s = 0; s < KS; ++s)
#pragma unroll
      for (int c = 0; c < CT; ++c)
        acc[c] = __builtin_amdgcn_mfma_f32_16x16x32_bf16(af[t][s], bfrag[c][s], acc[c], 0, 0, 0);

#pragma unroll
    for (int i = 0; i < 4; ++i) {
      const int rr = row0 + 4 * g + i;
      if (rr >= M) continue;
#pragma unroll
      for (int c = 0; c < CT; ++c) {
        const int col = colbase + 16 * c + j;
        float hc = bflo(A16[(size_t)rr * HID + col]);
        float z = fmaxf(fmaf(beta, acc[c][i], ob * hc), 0.f);
        C16[(size_t)rr * HID + col] = f2bf(z);
      }
    }
  }
}

// ---------------- fused lin2 + log_softmax via MFMA ----------------
static __global__ __launch_bounds__(256) void k_mlin2(
    const unsigned short* __restrict__ h16, const unsigned short* __restrict__ Wt2,
    const float* __restrict__ b2, float* __restrict__ out) {
  const int lane = threadIdx.x & 63;
  const int wid = threadIdx.x >> 6;
  const int j = lane & 15, g = lane >> 4;

  bf16x8 bfrag[3][4];
#pragma unroll
  for (int c = 0; c < 3; ++c)
#pragma unroll
    for (int s = 0; s < 4; ++s)
      bfrag[c][s] = *(const bf16x8*)(Wt2 + (size_t)(16 * c + j) * HID + 32 * s + 8 * g);

  float bb[3];
#pragma unroll
  for (int c = 0; c < 3; ++c) {
    int col = 16 * c + j;
    bb[c] = (col < OUTC) ? b2[col] : -1e30f;
  }

  const int wrow0 = blockIdx.x * 256 + wid * 64;
  const f32x4 zero = {0.f, 0.f, 0.f, 0.f};
#pragma unroll 1
  for (int t = 0; t < 4; ++t) {
    const int row0 = wrow0 + 16 * t;
    int rl = row0 + j;
    if (rl >= NN) rl = NN - 1;
    bf16x8 af[4];
#pragma unroll
    for (int s = 0; s < 4; ++s)
      af[s] = *(const bf16x8*)(h16 + (size_t)rl * HID + 32 * s + 8 * g);
    f32x4 acc[3] = {zero, zero, zero};
#pragma unroll
    for (int s = 0; s < 4; ++s)
#pragma unroll
      for (int c = 0; c < 3; ++c)
        acc[c] = __builtin_amdgcn_mfma_f32_16x16x32_bf16(af[s], bfrag[c][s], acc[c], 0, 0, 0);

#pragma unroll
    for (int i = 0; i < 4; ++i) {
      const int rr = row0 + 4 * g + i;
      float z0 = acc[0][i] + bb[0];
      float z1 = acc[1][i] + bb[1];
      float z2 = acc[2][i] + bb[2];
      float m = fmaxf(fmaxf(z0, z1), z2);
      m = fmaxf(m, __shfl_xor(m, 1));
      m = fmaxf(m, __shfl_xor(m, 2));
      m = fmaxf(m, __shfl_xor(m, 4));
      m = fmaxf(m, __shfl_xor(m, 8));
      float sum = __expf(z0 - m) + __expf(z1 - m) + __expf(z2 - m);
      sum += __shfl_xor(sum, 1);
      sum += __shfl_xor(sum, 2);
      sum += __shfl_xor(sum, 4);
      sum += __shfl_xor(sum, 8);
      float ls = m + logf(sum);
      if (rr < NN) {
        out[(size_t)rr * OUTC + j] = z0 - ls;
        out[(size_t)rr * OUTC + 16 + j] = z1 - ls;
        if (j < 8) out[(size_t)rr * OUTC + 32 + j] = z2 - ls;
      }
    }
  }
}

// ---------------- aggregation: hc16 = bf16(0.5*(A_hat @ h16) + 0.5*x016) ----------------
// 4 waves/block, one node per wave. Wave: 8 edge-slots x 8 lanes x 16 bf16 ch.
static __global__ __launch_bounds__(256) void k_agg(
    const unsigned short* __restrict__ h16, const unsigned short* __restrict__ x016,
    const float* __restrict__ dinv, const int* __restrict__ offs,
    const int2* __restrict__ edata, unsigned short* __restrict__ hc16) {
  int wid = threadIdx.x >> 6;
  int n = blockIdx.x * 4 + wid;
  if (n >= NN) return;
  int lane = threadIdx.x & 63;
  int cg = (lane & 7) * 16;  // 16-channel group base
  int slot = lane >> 3;      // 0..7

  int b = offs[n], e = offs[n + 1];
  float acc[16];
#pragma unroll
  for (int j = 0; j < 16; ++j) acc[j] = 0.f;

#define ACC16(PTR, W)                                                  \
  {                                                                    \
    const uint4 va = *(const uint4*)(PTR);                             \
    const uint4 vb = *(const uint4*)((PTR) + 8);                       \
    acc[0]  = fmaf((W), bflo(va.x), acc[0]);                           \
    acc[1]  = fmaf((W), bfhi(va.x), acc[1]);                           \
    acc[2]  = fmaf((W), bflo(va.y), acc[2]);                           \
    acc[3]  = fmaf((W), bfhi(va.y), acc[3]);                           \
    acc[4]  = fmaf((W), bflo(va.z), acc[4]);                           \
    acc[5]  = fmaf((W), bfhi(va.z), acc[5]);                           \
    acc[6]  = fmaf((W), bflo(va.w), acc[6]);                           \
    acc[7]  = fmaf((W), bfhi(va.w), acc[7]);                           \
    acc[8]  = fmaf((W), bflo(vb.x), acc[8]);                           \
    acc[9]  = fmaf((W), bfhi(vb.x), acc[9]);                           \
    acc[10] = fmaf((W), bflo(vb.y), acc[10]);                          \
    acc[11] = fmaf((W), bfhi(vb.y), acc[11]);                          \
    acc[12] = fmaf((W), bflo(vb.z), acc[12]);                          \
    acc[13] = fmaf((W), bfhi(vb.z), acc[13]);                          \
    acc[14] = fmaf((W), bflo(vb.w), acc[14]);                          \
    acc[15] = fmaf((W), bfhi(vb.w), acc[15]);                          \
  }

  if (slot == 0) {  // self loop
    float dn = dinv[n];
    ACC16(h16 + (size_t)n * HID + cg, dn * dn);
  }
  for (int i = b + slot; i < e; i += 8) {
    int2 ed = edata[i];
    float w = __int_as_float(ed.y);
    ACC16(h16 + (size_t)ed.x * HID + cg, w);
  }
#undef ACC16

#pragma unroll
  for (int j = 0; j < 16; ++j) {
    acc[j] += __shfl_xor(acc[j], 8);
    acc[j] += __shfl_xor(acc[j], 16);
    acc[j] += __shfl_xor(acc[j], 32);
  }

  if (lane < 8) {
    size_t nc = (size_t)n * HID + cg;
    const uint4 xa = *(const uint4*)(x016 + nc);
    const uint4 xb = *(const uint4*)(x016 + nc + 8);
    float o[16];
    o[0]  = 0.5f * acc[0]  + 0.5f * bflo(xa.x);
    o[1]  = 0.5f * acc[1]  + 0.5f * bfhi(xa.x);
    o[2]  = 0.5f * acc[2]  + 0.5f * bflo(xa.y);
    o[3]  = 0.5f * acc[3]  + 0.5f * bfhi(xa.y);
    o[4]  = 0.5f * acc[4]  + 0.5f * bflo(xa.z);
    o[5]  = 0.5f * acc[5]  + 0.5f * bfhi(xa.z);
    o[6]  = 0.5f * acc[6]  + 0.5f * bflo(xa.w);
    o[7]  = 0.5f * acc[7]  + 0.5f * bfhi(xa.w);
    o[8]  = 0.5f * acc[8]  + 0.5f * bflo(xb.x);
    o[9]  = 0.5f * acc[9]  + 0.5f * bfhi(xb.x);
    o[10] = 0.5f * acc[10] + 0.5f * bflo(xb.y);
    o[11] = 0.5f * acc[11] + 0.5f * bfhi(xb.y);
    o[12] = 0.5f * acc[12] + 0.5f * bflo(xb.z);
    o[13] = 0.5f * acc[13] + 0.5f * bfhi(xb.z);
    o[14] = 0.5f * acc[14] + 0.5f * bflo(xb.w);
    o[15] = 0.5f * acc[15] + 0.5f * bfhi(xb.w);
    ushort8_t_dummy:;
    unsigned short q[16];
#pragma unroll
    for (int j = 0; j < 16; ++j) q[j] = f2bf(o[j]);
    *(uint4*)(hc16 + nc) = *(const uint4*)&q[0];
    *(uint4*)(hc16 + nc + 8) = *(const uint4*)&q[8];
  }
}

// ---------------- host ----------------
extern "C" void kernel_launch(void* const* d_in, const int* in_sizes, int n_in,
                              void* d_out, int out_size, void* d_ws, size_t ws_size,
                              hipStream_t stream) {
  const float* x  = (const float*)d_in[0];
  const int*   ei = (const int*)d_in[1];
  const float* w1 = (const float*)d_in[2];
  const float* b1 = (const float*)d_in[3];
  const float* cw = (const float*)d_in[4];
  const float* w2 = (const float*)d_in[5];
  const float* b2 = (const float*)d_in[6];
  float* out = (float*)d_out;

  char* ws = (char*)d_ws;
  size_t o = 0;
  auto carve = [&](size_t bytes) {
    void* p = ws + o;
    o = (o + bytes + 255) & ~(size_t)255;
    return p;
  };
  int*   cnt    = (int*)carve((size_t)NN * 4);
  float* dinv   = (float*)carve((size_t)NN * 4);
  int*   offs   = (int*)carve((size_t)(NN + 1) * 4);
  int*   cursor = (int*)carve((size_t)NN * 4);
  int*   bsum   = (int*)carve(512 * 4);
  int2*  edata  = (int2*)carve((size_t)NE * 8);
  unsigned short* x016  = (unsigned short*)carve((size_t)NN * HID * 2);
  unsigned short* hb16  = (unsigned short*)carve((size_t)NN * HID * 2);
  unsigned short* hcb16 = (unsigned short*)carve((size_t)NN * HID * 2);
  unsigned short* wt1   = (unsigned short*)carve((size_t)INCH * HID * 2);
  unsigned short* wtl   = (unsigned short*)carve((size_t)NLAYERS * HID * HID * 2);
  unsigned short* wt2   = (unsigned short*)carve((size_t)48 * HID * 2);
  (void)ws_size; (void)in_sizes; (void)n_in; (void)out_size;

  const int TB = 256;
  const int gN = (NN + TB - 1) / TB;  // 391
  const int gE = (NE + TB - 1) / TB;  // 6250

  k_zero<<<gN, TB, 0, stream>>>(cnt);
  k_hist<<<gE, TB, 0, stream>>>(ei, cnt);
  k_dinv<<<gN, TB, 0, stream>>>(cnt, dinv, offs);
  k_scan1<<<gN, TB, 0, stream>>>(cnt, bsum);
  k_scan2<<<1, 512, 0, stream>>>(bsum, gN);
  k_scan3<<<gN, TB, 0, stream>>>(cnt, bsum, offs, cursor);
  k_fill<<<gE, TB, 0, stream>>>(ei, dinv, cursor, edata);

  k_cvtw<<<(INCH * HID + 255) / 256, 256, 0, stream>>>(w1, wt1, INCH);
  k_cvtw8<<<(NLAYERS * HID * HID + 255) / 256, 256, 0, stream>>>(cw, wtl);
  k_cvtw2<<<(48 * HID + 255) / 256, 256, 0, stream>>>(w2, wt2);

  k_lin1<<<(NN + 127) / 128, 256, 0, stream>>>(x, wt1, b1, x016, NN);

  const unsigned short* hin = x016;
  const int gA = (NN + 3) / 4;  // 25000
  for (int l = 0; l < NLAYERS; ++l) {
    float beta = logf(1.0f / (float)(l + 1) + 1.0f);
    k_agg<<<gA, 256, 0, stream>>>(hin, x016, dinv, offs, edata, hcb16);
    k_mgemm1<<<(NN + 127) / 128, 256, 0, stream>>>(
        hcb16, wtl + (size_t)l * HID * HID, beta, hb16, NN);
    hin = hb16;
  }
  k_mlin2<<<(NN + 255) / 256, 256, 0, stream>>>(hb16, wt2, b2, out);
}